// Round 1
// baseline (2463.954 us; speedup 1.0000x reference)
//
#include <hip/hip_runtime.h>
#include <math.h>

#define KD 32
#define CC 384
#define NB 8
#define CK 4
#define CGRP 4

__device__ __forceinline__ int refl(int i, int n){ i = (i<0)? -i : i; return (i>=n)? (2*n-2-i) : i; }

// Keys cubic, a = -0.5 (matches jax.image.resize 'cubic')
__device__ __forceinline__ float keysw(float t){
  if (t <= 1.0f) return ((1.5f*t - 2.5f)*t)*t + 1.0f;
  if (t <  2.0f) return ((-0.5f*t + 2.5f)*t - 4.0f)*t + 2.0f;
  return 0.0f;
}

// guidance [8,3,768,768] -> g2 [8,3,192,192] (4x4 mean)
__global__ __launch_bounds__(256) void pool4_kernel(const float* __restrict__ g, float* __restrict__ g2){
  int idx = blockIdx.x*256 + threadIdx.x;           // 884736 total
  int x = idx % 192; int y = (idx/192) % 192; int bc = idx/(192*192);
  const float* src = g + (size_t)bc*589824 + (size_t)(4*y)*768 + 4*x;
  float s = 0.f;
  #pragma unroll
  for (int r=0;r<4;r++){ float4 v = *(const float4*)(src + (size_t)r*768); s += (v.x+v.y)+(v.z+v.w); }
  g2[idx] = s * 0.0625f;
}

// g2 -> g1 [8,3,96,96] (2x2 mean)
__global__ __launch_bounds__(256) void pool2_kernel(const float* __restrict__ g2, float* __restrict__ g1){
  int idx = blockIdx.x*256 + threadIdx.x;           // 221184 total
  int x = idx % 96; int y = (idx/96) % 96; int bc = idx/(96*96);
  const float* src = g2 + (size_t)bc*36864 + (size_t)(2*y)*192 + 2*x;
  float2 a = *(const float2*)src; float2 b = *(const float2*)(src+192);
  g1[idx] = (a.x+a.y+b.x+b.y)*0.25f;
}

// g [B,3,S,S] -> projv [B,S,S,32]  (1x1 conv -> tanh-GELU -> 1x1 conv)
template<int S>
__global__ __launch_bounds__(256) void proj_kernel(const float* __restrict__ g,
    const float* __restrict__ w1, const float* __restrict__ b1,
    const float* __restrict__ w2, const float* __restrict__ b2,
    float* __restrict__ projv){
  __shared__ float sw1[KD*3], sb1[KD], sw2[KD*KD], sb2[KD];
  int t = threadIdx.x;
  if (t < KD*3) sw1[t] = w1[t];
  if (t < KD){ sb1[t]=b1[t]; sb2[t]=b2[t]; }
  for (int i=t;i<KD*KD;i+=256) sw2[i]=w2[i];
  __syncthreads();
  int idx = blockIdx.x*256 + t;                     // B*S*S exact
  int b = idx/(S*S); int px = idx - b*S*S;
  float g0  = g[(size_t)(b*3+0)*S*S + px];
  float g1v = g[(size_t)(b*3+1)*S*S + px];
  float g2v = g[(size_t)(b*3+2)*S*S + px];
  float h[KD];
  #pragma unroll
  for (int k=0;k<KD;k++){
    float a = sb1[k] + sw1[k*3]*g0 + sw1[k*3+1]*g1v + sw1[k*3+2]*g2v;
    float inner = 0.7978845608028654f*(a + 0.044715f*a*a*a);
    h[k] = 0.5f*a*(1.0f + tanhf(inner));
  }
  float* o = projv + (size_t)idx*KD;
  #pragma unroll
  for (int j=0;j<KD;j++){
    float acc = sb2[j];
    #pragma unroll
    for (int k=0;k<KD;k++) acc += sw2[j*KD+k]*h[k];
    o[j] = acc;
  }
}

// projv -> combined [B,S,S,49]: logits, softmax(temp*logits), * spatial, renorm
template<int S>
__global__ __launch_bounds__(256) void combined_kernel(const float* __restrict__ projv,
    const float* __restrict__ rtemp, const float* __restrict__ sigma,
    float* __restrict__ comb){
  int idx = blockIdx.x*256 + threadIdx.x;
  int b = idx/(S*S); int px = idx - b*S*S; int y = px/S; int x = px - y*S;
  float ctr[KD];
  { const float4* cp = (const float4*)(projv + (size_t)idx*KD);
    #pragma unroll
    for (int q=0;q<KD/4;q++){ float4 v = cp[q]; ctr[4*q]=v.x; ctr[4*q+1]=v.y; ctr[4*q+2]=v.z; ctr[4*q+3]=v.w; } }
  float tpos = expf(rtemp[0]); tpos = fminf(fmaxf(tpos, 1e-4f), 1e4f);
  float lg[49];
  #pragma unroll
  for (int p=0;p<49;p++){
    int dy = p/7 - 3, dx = p - (p/7)*7 - 3;
    int yy = refl(y+dy, S), xx = refl(x+dx, S);
    const float4* np = (const float4*)(projv + ((size_t)b*S*S + (size_t)yy*S + xx)*KD);
    float acc = 0.f;
    #pragma unroll
    for (int q=0;q<KD/4;q++){ float4 v = np[q]; acc += v.x*ctr[4*q] + v.y*ctr[4*q+1] + v.z*ctr[4*q+2] + v.w*ctr[4*q+3]; }
    lg[p] = acc * tpos;
  }
  float m = lg[0];
  #pragma unroll
  for (int p=1;p<49;p++) m = fmaxf(m, lg[p]);
  float E = 0.f;
  #pragma unroll
  for (int p=0;p<49;p++){ lg[p] = expf(lg[p]-m); E += lg[p]; }
  float invE = 1.0f/E;
  float sg = sigma[0];
  float inv2s = -0.5f/(sg*sg);
  float sv[7];
  #pragma unroll
  for (int i=0;i<7;i++){ float d = (float)(i-3)*(1.0f/3.0f); sv[i] = expf(d*d*inv2s); }
  float Ssum = 0.f;
  #pragma unroll
  for (int p=0;p<49;p++){ float cmb = (lg[p]*invE)*sv[p/7]*sv[p%7]; lg[p]=cmb; Ssum += cmb; }
  float inv = 1.0f/fmaxf(Ssum, 1e-7f);
  float* o = comb + (size_t)idx*49;
  #pragma unroll
  for (int p=0;p<49;p++) o[p] = lg[p]*inv;
}

// Fused: bicubic x2 upsample (jax-exact edge renorm) + per-pixel 7x7 adaptive conv.
// src [B,CC,N,N] (N=S/2), comb [B,S,S,49] -> out [B,CC,S,S]
template<int S>
__global__ __launch_bounds__(256) void jbu_apply_kernel(const float* __restrict__ src,
    const float* __restrict__ comb, float* __restrict__ out){
  const int N = S/2;
  int bz = blockIdx.z;
  int b = bz / CGRP;
  int cstart = (bz - b*CGRP)*(CC/CGRP);
  int ty0 = blockIdx.y*16, tx0 = blockIdx.x*16;
  int t = threadIdx.x;
  int ly = t>>4, lx = t&15;

  __shared__ float sload[CK][16][16];
  __shared__ float tmp[CK][16][22];
  __shared__ float hrbuf[22*22*CK];
  __shared__ float wrow[22][4], wcol[22][4];
  __shared__ int rbase[22], cbase[22], rmap[22], cmap[22];

  int r0 = max(0, ty0-3), r1 = min(S-1, ty0+18);
  int c0 = max(0, tx0-3), c1 = min(S-1, tx0+18);
  int HR_H = r1-r0+1, HR_W = c1-c0+1;
  int sy0 = (r0>>1)-2, sx0 = (c0>>1)-2;

  if (t < 22){ rmap[t] = refl(ty0 + t - 3, S) - r0; cmap[t] = refl(tx0 + t - 3, S) - c0; }
  if (t >= 32 && t < 32+HR_H){
    int i = t-32; int o = r0+i;
    int i1 = (o&1) ? (o>>1) : (o>>1)-1;          // floor(0.5*o - 0.25)
    float f = 0.5f*(float)o - 0.25f - (float)i1;
    float w0=keysw(f+1.0f), w1=keysw(f), w2=keysw(1.0f-f), w3=keysw(2.0f-f);
    int base = i1-1;
    float s = 0.f;
    if (base+0 < 0 || base+0 >= N) w0=0.f; else s += w0;
    if (base+1 < 0 || base+1 >= N) w1=0.f; else s += w1;
    if (base+2 < 0 || base+2 >= N) w2=0.f; else s += w2;
    if (base+3 < 0 || base+3 >= N) w3=0.f; else s += w3;
    float invs = 1.0f/s;
    wrow[i][0]=w0*invs; wrow[i][1]=w1*invs; wrow[i][2]=w2*invs; wrow[i][3]=w3*invs;
    rbase[i] = base - sy0;
  }
  if (t >= 64 && t < 64+HR_W){
    int i = t-64; int o = c0+i;
    int i1 = (o&1) ? (o>>1) : (o>>1)-1;
    float f = 0.5f*(float)o - 0.25f - (float)i1;
    float w0=keysw(f+1.0f), w1=keysw(f), w2=keysw(1.0f-f), w3=keysw(2.0f-f);
    int base = i1-1;
    float s = 0.f;
    if (base+0 < 0 || base+0 >= N) w0=0.f; else s += w0;
    if (base+1 < 0 || base+1 >= N) w1=0.f; else s += w1;
    if (base+2 < 0 || base+2 >= N) w2=0.f; else s += w2;
    if (base+3 < 0 || base+3 >= N) w3=0.f; else s += w3;
    float invs = 1.0f/s;
    wcol[i][0]=w0*invs; wcol[i][1]=w1*invs; wcol[i][2]=w2*invs; wcol[i][3]=w3*invs;
    cbase[i] = base - sx0;
  }
  __syncthreads();

  int rowoff[7], coloff[7];
  #pragma unroll
  for (int d=0; d<7; d++){ rowoff[d] = rmap[ly+d]*(22*CK); coloff[d] = cmap[lx+d]*CK; }

  float w49[49];
  { const float* cp = comb + (((size_t)b*S*S) + (size_t)(ty0+ly)*S + (tx0+lx))*49;
    #pragma unroll
    for (int p=0;p<49;p++) w49[p] = cp[p]; }

  int sy = min(max(sy0+ly,0),N-1), sx = min(max(sx0+lx,0),N-1);

  for (int cc0 = cstart; cc0 < cstart + CC/CGRP; cc0 += CK){
    __syncthreads();
    const float* sp = src + ((size_t)(b*CC + cc0)*N + sy)*N + sx;
    #pragma unroll
    for (int k=0;k<CK;k++) sload[k][ly][lx] = sp[(size_t)k*N*N];
    __syncthreads();
    for (int i=t; i < CK*16*HR_W; i+=256){
      int hx = i % HR_W; int rr = (i/HR_W)&15; int cc = i/(16*HR_W);
      int cb = cbase[hx];
      tmp[cc][rr][hx] = wcol[hx][0]*sload[cc][rr][cb] + wcol[hx][1]*sload[cc][rr][cb+1]
                      + wcol[hx][2]*sload[cc][rr][cb+2] + wcol[hx][3]*sload[cc][rr][cb+3];
    }
    __syncthreads();
    for (int i=t; i < HR_H*HR_W*CK; i+=256){
      int cc = i & (CK-1); int pos = i>>2; int hy = pos/HR_W; int hx = pos - hy*HR_W;
      int rb = rbase[hy];
      hrbuf[(hy*22+hx)*CK+cc] = wrow[hy][0]*tmp[cc][rb][hx] + wrow[hy][1]*tmp[cc][rb+1][hx]
                              + wrow[hy][2]*tmp[cc][rb+2][hx] + wrow[hy][3]*tmp[cc][rb+3][hx];
    }
    __syncthreads();
    float a0=0.f,a1=0.f,a2=0.f,a3=0.f;
    #pragma unroll
    for (int p=0;p<49;p++){
      int off = rowoff[p/7] + coloff[p%7];
      float4 h = *(const float4*)&hrbuf[off];
      float w = w49[p];
      a0 += w*h.x; a1 += w*h.y; a2 += w*h.z; a3 += w*h.w;
    }
    size_t ob = ((size_t)(b*CC + cc0)*S + (ty0+ly))*S + (tx0+lx);
    size_t ps = (size_t)S*S;
    out[ob] = a0; out[ob+ps] = a1; out[ob+2*ps] = a2; out[ob+3*ps] = a3;
  }
}

// W_eff = 0.1*proj_w@fixup_w + proj_w ; b_eff = 0.1*proj_w@fixup_b + proj_b
__global__ void weff_kernel(const float* __restrict__ pw, const float* __restrict__ pb,
                            const float* __restrict__ fw, const float* __restrict__ fb,
                            float* __restrict__ weff, float* __restrict__ beff){
  int o = blockIdx.x; int c = threadIdx.x;   // grid 256, block 384
  float acc = 0.f;
  for (int k=0;k<CC;k++) acc += pw[o*CC+k]*fw[(size_t)k*CC+c];
  weff[(size_t)o*CC+c] = 0.1f*acc + pw[o*CC+c];
  if (c==0){
    float a=0.f;
    for (int k=0;k<CC;k++) a += pw[o*CC+k]*fb[k];
    beff[o] = 0.1f*a + pb[o];
  }
}

// out[b,o,px] = b_eff[o] + sum_c W_eff[o,c]*s4[b,c,px]; M=256,K=384,N=36864/batch
__global__ __launch_bounds__(256) void final_conv_kernel(const float* __restrict__ s4,
    const float* __restrict__ weff, const float* __restrict__ beff, float* __restrict__ out){
  const int PX = 192*192;
  int b = blockIdx.z, m0 = blockIdx.y*128, n0 = blockIdx.x*128;
  int t = threadIdx.x;
  __shared__ float As[16][132];
  __shared__ float Bs[16][128];
  float acc[8][8];
  #pragma unroll
  for (int i=0;i<8;i++)
    #pragma unroll
    for (int j=0;j<8;j++) acc[i][j]=0.f;
  int tm0 = (t>>4)*8, tn0 = (t&15)*8;
  const float* Ab = weff + (size_t)m0*CC;
  const float* Bb = s4 + (size_t)b*CC*PX + n0;
  for (int k0=0; k0<CC; k0+=16){
    {
      int ra = t>>2, kc = (t&3)*4;
      float4 v0 = *(const float4*)&Ab[(size_t)ra*CC + k0+kc];
      float4 v1 = *(const float4*)&Ab[(size_t)(ra+64)*CC + k0+kc];
      As[kc+0][ra]=v0.x; As[kc+1][ra]=v0.y; As[kc+2][ra]=v0.z; As[kc+3][ra]=v0.w;
      As[kc+0][ra+64]=v1.x; As[kc+1][ra+64]=v1.y; As[kc+2][ra+64]=v1.z; As[kc+3][ra+64]=v1.w;
    }
    {
      int kr = t>>4, ncol = (t&15)*8;
      const float* bp = Bb + (size_t)(k0+kr)*PX + ncol;
      *(float4*)&Bs[kr][ncol]   = *(const float4*)bp;
      *(float4*)&Bs[kr][ncol+4] = *(const float4*)(bp+4);
    }
    __syncthreads();
    #pragma unroll
    for (int kk=0;kk<16;kk++){
      float av[8], bv[8];
      *(float4*)&av[0] = *(const float4*)&As[kk][tm0];
      *(float4*)&av[4] = *(const float4*)&As[kk][tm0+4];
      *(float4*)&bv[0] = *(const float4*)&Bs[kk][tn0];
      *(float4*)&bv[4] = *(const float4*)&Bs[kk][tn0+4];
      #pragma unroll
      for (int i=0;i<8;i++)
        #pragma unroll
        for (int j=0;j<8;j++) acc[i][j] += av[i]*bv[j];
    }
    __syncthreads();
  }
  #pragma unroll
  for (int i=0;i<8;i++){
    float be = beff[m0+tm0+i];
    float* op = out + ((size_t)(b*256 + m0+tm0+i))*PX + n0+tn0;
    float4 v0 = make_float4(acc[i][0]+be, acc[i][1]+be, acc[i][2]+be, acc[i][3]+be);
    float4 v1 = make_float4(acc[i][4]+be, acc[i][5]+be, acc[i][6]+be, acc[i][7]+be);
    *(float4*)op = v0; *(float4*)(op+4) = v1;
  }
}

extern "C" void kernel_launch(void* const* d_in, const int* in_sizes, int n_in,
                              void* d_out, int out_size, void* d_ws, size_t ws_size,
                              hipStream_t stream) {
  const float* source   = (const float*)d_in[0];
  const float* guidance = (const float*)d_in[1];
  const float* u1w1 = (const float*)d_in[2];
  const float* u1b1 = (const float*)d_in[3];
  const float* u1w2 = (const float*)d_in[4];
  const float* u1b2 = (const float*)d_in[5];
  const float* u1rt = (const float*)d_in[6];
  const float* u1sg = (const float*)d_in[7];
  const float* u2w1 = (const float*)d_in[8];
  const float* u2b1 = (const float*)d_in[9];
  const float* u2w2 = (const float*)d_in[10];
  const float* u2b2 = (const float*)d_in[11];
  const float* u2rt = (const float*)d_in[12];
  const float* u2sg = (const float*)d_in[13];
  const float* fixw = (const float*)d_in[14];
  const float* fixb = (const float*)d_in[15];
  const float* prjw = (const float*)d_in[16];
  const float* prjb = (const float*)d_in[17];
  float* out = (float*)d_out;

  float* ws    = (float*)d_ws;
  float* g2    = ws;                    // 884736
  float* g1    = g2    + 884736;        // 221184
  float* proj1 = g1    + 221184;        // 2359296
  float* comb1 = proj1 + 2359296;       // 3612672
  float* s2    = comb1 + 3612672;       // 28311552
  float* proj2 = s2    + 28311552;      // 9437184
  float* comb2 = proj2 + 9437184;       // 14450688
  float* s4    = comb2 + 14450688;      // 113246208
  float* weff  = s4    + 113246208;     // 98304
  float* beff  = weff  + 98304;         // 256

  pool4_kernel<<<3456,256,0,stream>>>(guidance, g2);
  pool2_kernel<<<864,256,0,stream>>>(g2, g1);

  proj_kernel<96><<<288,256,0,stream>>>(g1, u1w1, u1b1, u1w2, u1b2, proj1);
  combined_kernel<96><<<288,256,0,stream>>>(proj1, u1rt, u1sg, comb1);
  jbu_apply_kernel<96><<<dim3(6,6,8*CGRP),256,0,stream>>>(source, comb1, s2);

  proj_kernel<192><<<1152,256,0,stream>>>(g2, u2w1, u2b1, u2w2, u2b2, proj2);
  combined_kernel<192><<<1152,256,0,stream>>>(proj2, u2rt, u2sg, comb2);
  jbu_apply_kernel<192><<<dim3(12,12,8*CGRP),256,0,stream>>>(s2, comb2, s4);

  weff_kernel<<<256,384,0,stream>>>(prjw, prjb, fixw, fixb, weff, beff);
  final_conv_kernel<<<dim3(288,2,8),256,0,stream>>>(s4, weff, beff, out);
}

// Round 2
// 1693.458 us; speedup vs baseline: 1.4550x; 1.4550x over previous
//
#include <hip/hip_runtime.h>
#include <math.h>

#define KD 32
#define CC 384
#define PX1 (96*96)
#define PX2 (192*192)

typedef __attribute__((ext_vector_type(8))) short short8;
typedef __attribute__((ext_vector_type(4))) float floatx4;

__device__ __forceinline__ int refl(int i, int n){ i = (i<0)? -i : i; return (i>=n)? (2*n-2-i) : i; }

__device__ __forceinline__ float keysw(float t){
  if (t <= 1.0f) return ((1.5f*t - 2.5f)*t)*t + 1.0f;
  if (t <  2.0f) return ((-0.5f*t + 2.5f)*t - 4.0f)*t + 2.0f;
  return 0.0f;
}

__device__ __forceinline__ unsigned pack_bf16(float a, float b){
  unsigned ua = __float_as_uint(a), ub = __float_as_uint(b);
  ua = (ua + 0x7fffu + ((ua>>16)&1u)) >> 16;
  ub = (ub + 0x7fffu + ((ub>>16)&1u)) >> 16;
  return ua | (ub<<16);
}
__device__ __forceinline__ unsigned short bf16_1(float a){
  unsigned ua = __float_as_uint(a);
  return (unsigned short)((ua + 0x7fffu + ((ua>>16)&1u)) >> 16);
}

// guidance [8,3,768,768] -> g2 [8,3,192,192]
__global__ __launch_bounds__(256) void pool4_kernel(const float* __restrict__ g, float* __restrict__ g2){
  int idx = blockIdx.x*256 + threadIdx.x;
  int x = idx % 192; int y = (idx/192) % 192; int bc = idx/(192*192);
  const float* src = g + (size_t)bc*589824 + (size_t)(4*y)*768 + 4*x;
  float s = 0.f;
  #pragma unroll
  for (int r=0;r<4;r++){ float4 v = *(const float4*)(src + (size_t)r*768); s += (v.x+v.y)+(v.z+v.w); }
  g2[idx] = s * 0.0625f;
}

// g2 -> g1 [8,3,96,96]
__global__ __launch_bounds__(256) void pool2_kernel(const float* __restrict__ g2, float* __restrict__ g1){
  int idx = blockIdx.x*256 + threadIdx.x;
  int x = idx % 96; int y = (idx/96) % 96; int bc = idx/(96*96);
  const float* src = g2 + (size_t)bc*36864 + (size_t)(2*y)*192 + 2*x;
  float2 a = *(const float2*)src; float2 b = *(const float2*)(src+192);
  g1[idx] = (a.x+a.y+b.x+b.y)*0.25f;
}

// Fused proj (3->32 gelu ->32) + 49-dot + softmax + spatial + renorm.
// g [B,3,S,S] -> comb planar [B,49,S,S]
template<int S>
__global__ __launch_bounds__(256) void projcomb_kernel(const float* __restrict__ g,
    const float* __restrict__ w1, const float* __restrict__ b1,
    const float* __restrict__ w2, const float* __restrict__ b2,
    const float* __restrict__ rtemp, const float* __restrict__ sigma,
    float* __restrict__ comb){
  __shared__ float projT[484][36];
  __shared__ float sw1[KD*3], sb1[KD], sw2[KD*KD], sb2[KD];
  int t = threadIdx.x;
  if (t < KD*3) sw1[t] = w1[t];
  if (t < KD){ sb1[t]=b1[t]; sb2[t]=b2[t]; }
  for (int i=t;i<KD*KD;i+=256) sw2[i]=w2[i];
  __syncthreads();
  int b = blockIdx.z; int y0 = blockIdx.y*16, x0 = blockIdx.x*16;
  for (int i=t; i<484; i+=256){
    int hy = i/22, hx = i-hy*22;
    int gy = refl(y0+hy-3, S), gx = refl(x0+hx-3, S);
    size_t base = (size_t)b*3*S*S + (size_t)gy*S + gx;
    float g0 = g[base], g1v = g[base + (size_t)S*S], g2v = g[base + (size_t)2*S*S];
    float h[KD];
    #pragma unroll
    for (int k=0;k<KD;k++){
      float a = sb1[k] + sw1[k*3]*g0 + sw1[k*3+1]*g1v + sw1[k*3+2]*g2v;
      float inner = 0.7978845608028654f*(a + 0.044715f*a*a*a);
      h[k] = 0.5f*a*(1.0f + tanhf(inner));
    }
    #pragma unroll
    for (int j=0;j<KD;j++){
      float acc = sb2[j];
      #pragma unroll
      for (int k=0;k<KD;k++) acc += sw2[j*KD+k]*h[k];
      projT[i][j] = acc;
    }
  }
  __syncthreads();
  int ly = t>>4, lx = t&15;
  float ctr[KD];
  { const float4* cp = (const float4*)&projT[(ly+3)*22 + lx+3][0];
    #pragma unroll
    for (int q=0;q<KD/4;q++){ float4 v = cp[q]; ctr[4*q]=v.x; ctr[4*q+1]=v.y; ctr[4*q+2]=v.z; ctr[4*q+3]=v.w; } }
  float tpos = expf(rtemp[0]); tpos = fminf(fmaxf(tpos, 1e-4f), 1e4f);
  float lg[49];
  #pragma unroll
  for (int p=0;p<49;p++){
    int pix2 = (ly + p/7)*22 + lx + (p - (p/7)*7);
    const float4* np = (const float4*)&projT[pix2][0];
    float acc = 0.f;
    #pragma unroll
    for (int q=0;q<KD/4;q++){ float4 v = np[q]; acc += v.x*ctr[4*q] + v.y*ctr[4*q+1] + v.z*ctr[4*q+2] + v.w*ctr[4*q+3]; }
    lg[p] = acc * tpos;
  }
  float m = lg[0];
  #pragma unroll
  for (int p=1;p<49;p++) m = fmaxf(m, lg[p]);
  float E = 0.f;
  #pragma unroll
  for (int p=0;p<49;p++){ lg[p] = expf(lg[p]-m); E += lg[p]; }
  float invE = 1.0f/E;
  float sg = sigma[0];
  float inv2s = -0.5f/(sg*sg);
  float sv[7];
  #pragma unroll
  for (int i=0;i<7;i++){ float d = (float)(i-3)*(1.0f/3.0f); sv[i] = expf(d*d*inv2s); }
  float Ssum = 0.f;
  #pragma unroll
  for (int p=0;p<49;p++){ float cmb = (lg[p]*invE)*sv[p/7]*sv[p%7]; lg[p]=cmb; Ssum += cmb; }
  float inv = 1.0f/fmaxf(Ssum, 1e-7f);
  float* o = comb + (size_t)b*49*S*S + (size_t)(y0+ly)*S + (x0+lx);
  #pragma unroll
  for (int p=0;p<49;p++) o[(size_t)p*S*S] = lg[p]*inv;
}

// ---- Stage-1 JBU apply: f32, CK=4, conflict-free layouts. S=96, N=48.
__global__ __launch_bounds__(256) void jbu1_kernel(const float* __restrict__ src,
    const float* __restrict__ comb, float* __restrict__ out){
  const int S = 96, N = 48;
  int bz = blockIdx.z;
  int b = bz >> 2;
  int cstart = (bz & 3)*96;
  int ty0 = blockIdx.y*16, tx0 = blockIdx.x*16;
  int t = threadIdx.x;
  int ly = t>>4, lx = t&15;

  __shared__ float sload[16][16][5];
  __shared__ float tmp[16][22][5];
  __shared__ float hrbuf[22*22*4];
  __shared__ float wrow[22][4], wcol[22][4];
  __shared__ int rbase[22], cbase[22], rmap[22], cmap[22];

  int r0 = max(0, ty0-3), r1 = min(S-1, ty0+18);
  int c0 = max(0, tx0-3), c1 = min(S-1, tx0+18);
  int HR_H = r1-r0+1, HR_W = c1-c0+1;
  int sy0 = (r0>>1)-2, sx0 = (c0>>1)-2;

  if (t < 22){ rmap[t] = refl(ty0 + t - 3, S) - r0; cmap[t] = refl(tx0 + t - 3, S) - c0; }
  if (t >= 32 && t < 32+HR_H){
    int i = t-32; int o = r0+i;
    int i1 = (o&1) ? (o>>1) : (o>>1)-1;
    float f = 0.5f*(float)o - 0.25f - (float)i1;
    float w0=keysw(f+1.0f), w1=keysw(f), w2=keysw(1.0f-f), w3=keysw(2.0f-f);
    int base = i1-1;
    float s = 0.f;
    if (base+0 < 0 || base+0 >= N) w0=0.f; else s += w0;
    if (base+1 < 0 || base+1 >= N) w1=0.f; else s += w1;
    if (base+2 < 0 || base+2 >= N) w2=0.f; else s += w2;
    if (base+3 < 0 || base+3 >= N) w3=0.f; else s += w3;
    float invs = 1.0f/s;
    wrow[i][0]=w0*invs; wrow[i][1]=w1*invs; wrow[i][2]=w2*invs; wrow[i][3]=w3*invs;
    rbase[i] = base - sy0;
  }
  if (t >= 64 && t < 64+HR_W){
    int i = t-64; int o = c0+i;
    int i1 = (o&1) ? (o>>1) : (o>>1)-1;
    float f = 0.5f*(float)o - 0.25f - (float)i1;
    float w0=keysw(f+1.0f), w1=keysw(f), w2=keysw(1.0f-f), w3=keysw(2.0f-f);
    int base = i1-1;
    float s = 0.f;
    if (base+0 < 0 || base+0 >= N) w0=0.f; else s += w0;
    if (base+1 < 0 || base+1 >= N) w1=0.f; else s += w1;
    if (base+2 < 0 || base+2 >= N) w2=0.f; else s += w2;
    if (base+3 < 0 || base+3 >= N) w3=0.f; else s += w3;
    float invs = 1.0f/s;
    wcol[i][0]=w0*invs; wcol[i][1]=w1*invs; wcol[i][2]=w2*invs; wcol[i][3]=w3*invs;
    cbase[i] = base - sx0;
  }
  __syncthreads();

  int rowoff[7], coloff[7];
  #pragma unroll
  for (int d=0; d<7; d++){ rowoff[d] = rmap[ly+d]*22; coloff[d] = cmap[lx+d]; }

  float w49[49];
  { const float* cp = comb + (size_t)b*49*S*S + (size_t)(ty0+ly)*S + (tx0+lx);
    #pragma unroll
    for (int p=0;p<49;p++) w49[p] = cp[(size_t)p*S*S]; }

  int sy = min(max(sy0+ly,0),N-1), sx = min(max(sx0+lx,0),N-1);
  const float4* hr4 = (const float4*)hrbuf;

  for (int cc0 = cstart; cc0 < cstart + 96; cc0 += 4){
    __syncthreads();
    const float* sp = src + ((size_t)(b*CC + cc0)*N + sy)*N + sx;
    #pragma unroll
    for (int k=0;k<4;k++) sload[ly][lx][k] = sp[(size_t)k*N*N];
    __syncthreads();
    for (int i=t; i < 16*HR_W*4; i+=256){
      int cc = i&3; int pos = i>>2; int hx = pos % HR_W; int rr = pos / HR_W;
      int cb = cbase[hx];
      tmp[rr][hx][cc] = wcol[hx][0]*sload[rr][cb][cc] + wcol[hx][1]*sload[rr][cb+1][cc]
                      + wcol[hx][2]*sload[rr][cb+2][cc] + wcol[hx][3]*sload[rr][cb+3][cc];
    }
    __syncthreads();
    for (int i=t; i < HR_H*HR_W*4; i+=256){
      int cc = i&3; int pos = i>>2; int hy = pos / HR_W; int hx = pos - hy*HR_W;
      int rb = rbase[hy];
      hrbuf[(hy*22+hx)*4+cc] = wrow[hy][0]*tmp[rb][hx][cc] + wrow[hy][1]*tmp[rb+1][hx][cc]
                             + wrow[hy][2]*tmp[rb+2][hx][cc] + wrow[hy][3]*tmp[rb+3][hx][cc];
    }
    __syncthreads();
    float a0=0.f,a1=0.f,a2=0.f,a3=0.f;
    #pragma unroll
    for (int p=0;p<49;p++){
      float4 h = hr4[rowoff[p/7] + coloff[p%7]];
      float w = w49[p];
      a0 += w*h.x; a1 += w*h.y; a2 += w*h.z; a3 += w*h.w;
    }
    size_t ob = ((size_t)(b*CC + cc0)*S + (ty0+ly))*S + (tx0+lx);
    size_t ps = (size_t)S*S;
    out[ob] = a0; out[ob+ps] = a1; out[ob+2*ps] = a2; out[ob+3*ps] = a3;
  }
}

// ---- Stage-2 JBU apply: bf16 hr, CK=8. S=192, N=96. Output channel-blocked bf16 [b][c/8][pix][8].
__global__ __launch_bounds__(256) void jbu2_kernel(const float* __restrict__ src,
    const float* __restrict__ comb, unsigned short* __restrict__ outT){
  const int S = 192, N = 96;
  int bz = blockIdx.z;
  int b = bz >> 2;
  int cstart = (bz & 3)*96;
  int ty0 = blockIdx.y*16, tx0 = blockIdx.x*16;
  int t = threadIdx.x;
  int ly = t>>4, lx = t&15;

  __shared__ float sload[16][16][10];
  __shared__ float tmp[16][22][10];
  __shared__ unsigned short hrbuf[22*22*8];
  __shared__ float wrow[22][4], wcol[22][4];
  __shared__ int rbase[22], cbase[22], rmap[22], cmap[22];

  int r0 = max(0, ty0-3), r1 = min(S-1, ty0+18);
  int c0 = max(0, tx0-3), c1 = min(S-1, tx0+18);
  int HR_H = r1-r0+1, HR_W = c1-c0+1;
  int sy0 = (r0>>1)-2, sx0 = (c0>>1)-2;

  if (t < 22){ rmap[t] = refl(ty0 + t - 3, S) - r0; cmap[t] = refl(tx0 + t - 3, S) - c0; }
  if (t >= 32 && t < 32+HR_H){
    int i = t-32; int o = r0+i;
    int i1 = (o&1) ? (o>>1) : (o>>1)-1;
    float f = 0.5f*(float)o - 0.25f - (float)i1;
    float w0=keysw(f+1.0f), w1=keysw(f), w2=keysw(1.0f-f), w3=keysw(2.0f-f);
    int base = i1-1;
    float s = 0.f;
    if (base+0 < 0 || base+0 >= N) w0=0.f; else s += w0;
    if (base+1 < 0 || base+1 >= N) w1=0.f; else s += w1;
    if (base+2 < 0 || base+2 >= N) w2=0.f; else s += w2;
    if (base+3 < 0 || base+3 >= N) w3=0.f; else s += w3;
    float invs = 1.0f/s;
    wrow[i][0]=w0*invs; wrow[i][1]=w1*invs; wrow[i][2]=w2*invs; wrow[i][3]=w3*invs;
    rbase[i] = base - sy0;
  }
  if (t >= 64 && t < 64+HR_W){
    int i = t-64; int o = c0+i;
    int i1 = (o&1) ? (o>>1) : (o>>1)-1;
    float f = 0.5f*(float)o - 0.25f - (float)i1;
    float w0=keysw(f+1.0f), w1=keysw(f), w2=keysw(1.0f-f), w3=keysw(2.0f-f);
    int base = i1-1;
    float s = 0.f;
    if (base+0 < 0 || base+0 >= N) w0=0.f; else s += w0;
    if (base+1 < 0 || base+1 >= N) w1=0.f; else s += w1;
    if (base+2 < 0 || base+2 >= N) w2=0.f; else s += w2;
    if (base+3 < 0 || base+3 >= N) w3=0.f; else s += w3;
    float invs = 1.0f/s;
    wcol[i][0]=w0*invs; wcol[i][1]=w1*invs; wcol[i][2]=w2*invs; wcol[i][3]=w3*invs;
    cbase[i] = base - sx0;
  }
  __syncthreads();

  int rowoff[7], coloff[7];
  #pragma unroll
  for (int d=0; d<7; d++){ rowoff[d] = rmap[ly+d]*22; coloff[d] = cmap[lx+d]; }

  float w49[49];
  { const float* cp = comb + (size_t)b*49*S*S + (size_t)(ty0+ly)*S + (tx0+lx);
    #pragma unroll
    for (int p=0;p<49;p++) w49[p] = cp[(size_t)p*S*S]; }

  int sy = min(max(sy0+ly,0),N-1), sx = min(max(sx0+lx,0),N-1);
  int pix = (ty0+ly)*S + (tx0+lx);
  const uint4* hr4 = (const uint4*)hrbuf;

  for (int step = 0; step < 12; step++){
    int cc0 = cstart + step*8;
    __syncthreads();
    const float* sp = src + ((size_t)(b*CC + cc0)*N + sy)*N + sx;
    #pragma unroll
    for (int k=0;k<8;k++) sload[ly][lx][k] = sp[(size_t)k*N*N];
    __syncthreads();
    for (int i=t; i < 16*HR_W*8; i+=256){
      int cc = i&7; int pos = i>>3; int hx = pos % HR_W; int rr = pos / HR_W;
      int cb = cbase[hx];
      tmp[rr][hx][cc] = wcol[hx][0]*sload[rr][cb][cc] + wcol[hx][1]*sload[rr][cb+1][cc]
                      + wcol[hx][2]*sload[rr][cb+2][cc] + wcol[hx][3]*sload[rr][cb+3][cc];
    }
    __syncthreads();
    for (int i=t; i < HR_H*HR_W*4; i+=256){
      int ccp = i&3; int pos = i>>2; int hy = pos / HR_W; int hx = pos - hy*HR_W;
      int rb = rbase[hy]; int cc = 2*ccp;
      float v0 = wrow[hy][0]*tmp[rb][hx][cc] + wrow[hy][1]*tmp[rb+1][hx][cc]
               + wrow[hy][2]*tmp[rb+2][hx][cc] + wrow[hy][3]*tmp[rb+3][hx][cc];
      float v1 = wrow[hy][0]*tmp[rb][hx][cc+1] + wrow[hy][1]*tmp[rb+1][hx][cc+1]
               + wrow[hy][2]*tmp[rb+2][hx][cc+1] + wrow[hy][3]*tmp[rb+3][hx][cc+1];
      ((unsigned*)hrbuf)[(hy*22+hx)*4 + ccp] = pack_bf16(v0, v1);
    }
    __syncthreads();
    float a0=0.f,a1=0.f,a2=0.f,a3=0.f,a4=0.f,a5=0.f,a6=0.f,a7=0.f;
    #pragma unroll
    for (int p=0;p<49;p++){
      uint4 h = hr4[rowoff[p/7] + coloff[p%7]];
      float w = w49[p];
      a0 += w*__uint_as_float(h.x<<16); a1 += w*__uint_as_float(h.x & 0xffff0000u);
      a2 += w*__uint_as_float(h.y<<16); a3 += w*__uint_as_float(h.y & 0xffff0000u);
      a4 += w*__uint_as_float(h.z<<16); a5 += w*__uint_as_float(h.z & 0xffff0000u);
      a6 += w*__uint_as_float(h.w<<16); a7 += w*__uint_as_float(h.w & 0xffff0000u);
    }
    int cg = cc0 >> 3;
    uint4 st;
    st.x = pack_bf16(a0,a1); st.y = pack_bf16(a2,a3);
    st.z = pack_bf16(a4,a5); st.w = pack_bf16(a6,a7);
    *(uint4*)(outT + ((size_t)(b*48 + cg)*PX2 + pix)*8) = st;
  }
}

// W_eff (bf16) = 0.1*proj_w@fixup_w + proj_w ; b_eff (f32)
__global__ void weff_kernel(const float* __restrict__ pw, const float* __restrict__ pb,
                            const float* __restrict__ fw, const float* __restrict__ fb,
                            unsigned short* __restrict__ weffh, float* __restrict__ beff){
  int o = blockIdx.x; int c = threadIdx.x;
  float acc = 0.f;
  for (int k=0;k<CC;k++) acc += pw[o*CC+k]*fw[(size_t)k*CC+c];
  weffh[(size_t)o*CC+c] = bf16_1(0.1f*acc + pw[o*CC+c]);
  if (c==0){
    float a=0.f;
    for (int k=0;k<CC;k++) a += pw[o*CC+k]*fb[k];
    beff[o] = 0.1f*a + pb[o];
  }
}

// MFMA GEMM: out[b,m,pix] = beff[m] + sum_c Weff[m,c]*s4T[b,pix,c]
// A = Weff bf16 [256][384]; B = s4T channel-blocked bf16 [b][48][PX2][8]
__global__ __launch_bounds__(256) void gemm_kernel(const unsigned short* __restrict__ s4T,
    const unsigned short* __restrict__ weffh, const float* __restrict__ beff,
    float* __restrict__ out){
  __shared__ unsigned short As[128][40];
  __shared__ unsigned short Bs[128][40];
  int t = threadIdx.x;
  int b = blockIdx.z, m0 = blockIdx.y*128, n0 = blockIdx.x*128;
  int lane = t & 63, wid = t >> 6;
  int wm = wid >> 1, wn = wid & 1;
  floatx4 acc[4][4];
  #pragma unroll
  for (int i=0;i<4;i++)
    #pragma unroll
    for (int j=0;j<4;j++) acc[i][j] = (floatx4){0.f,0.f,0.f,0.f};

  for (int ks=0; ks<12; ks++){
    __syncthreads();
    #pragma unroll
    for (int it=0; it<2; it++){
      int idx = t + it*256;
      int m = idx>>2, ki = idx&3;
      uint4 va = *(const uint4*)(weffh + (size_t)(m0+m)*CC + ks*32 + ki*8);
      *(uint4*)&As[m][ki*8] = va;
      int pix = idx & 127, cbi = idx >> 7;
      uint4 vb = *(const uint4*)(s4T + ((size_t)(b*48 + ks*4 + cbi)*PX2 + n0 + pix)*8);
      *(uint4*)&Bs[pix][cbi*8] = vb;
    }
    __syncthreads();
    short8 af[4], bf[4];
    int kw = (lane>>4)*8;
    #pragma unroll
    for (int mi=0;mi<4;mi++) af[mi] = *(const short8*)&As[wm*64 + mi*16 + (lane&15)][kw];
    #pragma unroll
    for (int ni=0;ni<4;ni++) bf[ni] = *(const short8*)&Bs[wn*64 + ni*16 + (lane&15)][kw];
    #pragma unroll
    for (int mi=0;mi<4;mi++)
      #pragma unroll
      for (int ni=0;ni<4;ni++)
        acc[mi][ni] = __builtin_amdgcn_mfma_f32_16x16x32_bf16(af[mi], bf[ni], acc[mi][ni], 0, 0, 0);
  }

  #pragma unroll
  for (int mi=0;mi<4;mi++){
    int rowbase = m0 + wm*64 + mi*16 + (lane>>4)*4;
    float be[4];
    #pragma unroll
    for (int r=0;r<4;r++) be[r] = beff[rowbase+r];
    #pragma unroll
    for (int ni=0;ni<4;ni++){
      int col = n0 + wn*64 + ni*16 + (lane&15);
      #pragma unroll
      for (int r=0;r<4;r++)
        out[((size_t)(b*256) + rowbase + r)*PX2 + col] = acc[mi][ni][r] + be[r];
    }
  }
}

extern "C" void kernel_launch(void* const* d_in, const int* in_sizes, int n_in,
                              void* d_out, int out_size, void* d_ws, size_t ws_size,
                              hipStream_t stream) {
  const float* source   = (const float*)d_in[0];
  const float* guidance = (const float*)d_in[1];
  const float* u1w1 = (const float*)d_in[2];
  const float* u1b1 = (const float*)d_in[3];
  const float* u1w2 = (const float*)d_in[4];
  const float* u1b2 = (const float*)d_in[5];
  const float* u1rt = (const float*)d_in[6];
  const float* u1sg = (const float*)d_in[7];
  const float* u2w1 = (const float*)d_in[8];
  const float* u2b1 = (const float*)d_in[9];
  const float* u2w2 = (const float*)d_in[10];
  const float* u2b2 = (const float*)d_in[11];
  const float* u2rt = (const float*)d_in[12];
  const float* u2sg = (const float*)d_in[13];
  const float* fixw = (const float*)d_in[14];
  const float* fixb = (const float*)d_in[15];
  const float* prjw = (const float*)d_in[16];
  const float* prjb = (const float*)d_in[17];
  float* out = (float*)d_out;

  float* ws    = (float*)d_ws;
  float* g2    = ws;                      // 884736
  float* g1    = g2    + 884736;          // 221184
  float* comb1 = g1    + 221184;          // 8*49*9216   = 3612672
  float* s2    = comb1 + 3612672;         // 28311552
  float* comb2 = s2    + 28311552;        // 8*49*36864  = 14450688
  float* s4f   = comb2 + 14450688;        // s4T bf16: 113246208 u16 = 56623104 floats
  unsigned short* s4T = (unsigned short*)s4f;
  float* wef   = s4f   + 56623104;        // weffh bf16: 98304 u16 = 49152 floats
  unsigned short* weffh = (unsigned short*)wef;
  float* beff  = wef   + 49152;           // 256

  pool4_kernel<<<3456,256,0,stream>>>(guidance, g2);
  pool2_kernel<<<864,256,0,stream>>>(g2, g1);

  projcomb_kernel<96><<<dim3(6,6,8),256,0,stream>>>(g1, u1w1, u1b1, u1w2, u1b2, u1rt, u1sg, comb1);
  jbu1_kernel<<<dim3(6,6,32),256,0,stream>>>(source, comb1, s2);

  projcomb_kernel<192><<<dim3(12,12,8),256,0,stream>>>(g2, u2w1, u2b1, u2w2, u2b2, u2rt, u2sg, comb2);
  jbu2_kernel<<<dim3(12,12,32),256,0,stream>>>(s2, comb2, s4T);

  weff_kernel<<<256,384,0,stream>>>(prjw, prjb, fixw, fixb, weffh, beff);
  gemm_kernel<<<dim3(288,2,8),256,0,stream>>>(s4T, weffh, beff, out);
}